// Round 12
// baseline (645.225 us; speedup 1.0000x reference)
//
#include <hip/hip_runtime.h>
#include <cmath>

#define B_ 32
#define N_ 64
#define H_ 256
#define G3_ 768           // 3*H
#define INTER_ 912        // 2H + 6C + C1
#define KP_ 928           // INTER_ padded to 29*32 for bf16 MFMA GEMM
#define FCIN_ 2992        // 3*INTER + H
#define GRED_ 2736        // 3*INTER (f reductions part of g)

#define PADA 264          // hA row stride (bf16 elems)
#define PADX 72           // xA row stride (bf16 elems)

typedef __attribute__((ext_vector_type(8))) short short8;
typedef __attribute__((ext_vector_type(4))) short sshort4;
typedef __attribute__((ext_vector_type(4))) float float4v;

#define MFMA __builtin_amdgcn_mfma_f32_16x16x32_bf16

// single-instruction transcendentals: v_exp_f32 is exp2, v_rcp_f32
__device__ __forceinline__ float sigmoid_f(float x) {
    return __builtin_amdgcn_rcpf(1.0f + __builtin_amdgcn_exp2f(-1.44269504f * x));
}
__device__ __forceinline__ float tanh_fast(float x) {
    return 1.0f - 2.0f * __builtin_amdgcn_rcpf(1.0f + __builtin_amdgcn_exp2f(2.88539008f * x));
}
__device__ __forceinline__ unsigned f2bf_bits(float x) {
    unsigned u = __float_as_uint(x);
    return (u + 0x7fffu + ((u >> 16) & 1u)) >> 16;
}
__device__ __forceinline__ short f2bf(float x) { return (short)f2bf_bits(x); }

// ---------------------------------------------------------------------------
// prep: (a) Bfrag   = gru2d weights, fragment-major bf16 (layout verified R2)
//       (b) Bfrag1  = gru1d Whh, same pack (8 kt)
//       (c) Bfrag1W = gru1d Wih (768 x 912), same pack, K zero-padded to 928
//       (d) fc1Wt transpose
//       (e) x1 copy -> f[:, 0:16] AND fbf[:, 0:16] (bf16), + fbf K-pad
// Fragment layout: [kt][ntile(48)][lane(64)][j(8)] bf16; value = W[n][k] with
// n = ntile*16 + (lane&15), k = kt*32 + (lane>>4)*8 + j.
// ---------------------------------------------------------------------------
__global__ __launch_bounds__(256) void prep_kernel(
        const float* __restrict__ Whh2, const float* __restrict__ Wih2,
        const float* __restrict__ Whh1, const float* __restrict__ Wih1,
        const float* __restrict__ fc1W, const float* __restrict__ x1,
        short* __restrict__ Bfrag, short* __restrict__ Bfrag1,
        short* __restrict__ Bfrag1W, float* __restrict__ fc1Wt,
        float* __restrict__ f, short* __restrict__ fbf) {
    int idx = blockIdx.x * 256 + threadIdx.x;
    if (idx < 10 * 48 * 64 * 8) {
        int j = idx & 7, lane = (idx >> 3) & 63, tile = idx >> 9;
        int nt = tile % 48, kt = tile / 48;
        int n = nt * 16 + (lane & 15);
        int kb = (lane >> 4) * 8 + j;
        float v = (kt < 8) ? Whh2[n * 256 + kt * 32 + kb]
                           : Wih2[n * 64 + (kt - 8) * 32 + kb];
        Bfrag[idx] = f2bf(v);
    }
    if (idx < 8 * 48 * 64 * 8) {
        int j = idx & 7, lane = (idx >> 3) & 63, tile = idx >> 9;
        int nt = tile % 48, kt = tile / 48;
        int n = nt * 16 + (lane & 15);
        int k = kt * 32 + (lane >> 4) * 8 + j;
        Bfrag1[idx] = f2bf(Whh1[n * 256 + k]);
    }
    if (idx < 29 * 48 * 64 * 8) {
        int j = idx & 7, lane = (idx >> 3) & 63, tile = idx >> 9;
        int nt = tile % 48, kt = tile / 48;
        int n = nt * 16 + (lane & 15);
        int k = kt * 32 + (lane >> 4) * 8 + j;
        Bfrag1W[idx] = (k < INTER_) ? f2bf(Wih1[n * INTER_ + k]) : (short)0;
    }
    if (idx < FCIN_ * 256) {
        int o = idx & 255, i = idx >> 8;
        fc1Wt[idx] = fc1W[o * FCIN_ + i];
    }
    if (idx < 2048 * 16) {
        int bj = idx >> 4, c = idx & 15;
        float v = x1[idx];
        f[bj * INTER_ + c] = v;
        fbf[bj * KP_ + c] = f2bf(v);
        fbf[bj * KP_ + 912 + c] = 0;   // zero-pad K 912..927
    }
}

// ---------------------------------------------------------------------------
// gru2d R12: R10 dataflow + GATE-GROUPED MFMA (validated on gru1d in R11):
// G1(R: 20 MFMA) -> G2(Z: 20) -> {r,z sigmoids} -> G3(N: 20) -> update.
// The 16 sigmoids issue on the VALU/trans pipe while G3's MFMAs occupy the
// matrix pipe. Chain-internal accumulation order unchanged -> bit-identical.
// asm memory clobbers between groups force hA re-reads (prevents CSE from
// keeping 40 extra regs live). Bx loaded per-group (4 frags) not upfront.
// Fused d[] reductions + direct fbf epilogue writes kept from R10.
// ---------------------------------------------------------------------------
__global__ __launch_bounds__(512, 1) void gru2d_mfma(
        const float* __restrict__ states,
        const int* __restrict__ perm1, const int* __restrict__ perm2,
        const short* __restrict__ Bfrag,
        const float* __restrict__ bih, const float* __restrict__ bhh,
        float* __restrict__ f, short* __restrict__ fbf) {
    __shared__ short hA[2][16 * PADA];
    __shared__ short xA[2][16 * PADX];
    __shared__ short8 Blds[2 * 48 * 64];
    __shared__ int perms[1024];

    const int tid = threadIdx.x;
    const int lane = tid & 63;
    const int w = tid >> 6;
    const int m = lane & 15;
    const int q = lane >> 4;
    const bool sd2 = blockIdx.x >= 128;
    const int sblock = (blockIdx.x & 127) * 16;

    for (int i = tid; i < 1024; i += 512) {
        int r = i >> 6, t = i & 63;
        int qq = (sblock + r) & 63;
        perms[i] = sd2 ? perm2[qq * 64 + t] : perm1[qq * 64 + t];
    }
    for (int i = tid; i < 16 * PADA; i += 512) hA[0][i] = 0;
    {
        const uint4* src = (const uint4*)(Bfrag + 6 * 48 * 64 * 8);
        uint4* dst = (uint4*)Blds;
        #pragma unroll
        for (int rep = 0; rep < 12; ++rep)
            dst[tid + rep * 512] = src[tid + rep * 512];
    }

    const short8* Bf8 = (const short8*)Bfrag;
    short8 Bres[36];
    #pragma unroll
    for (int kt = 0; kt < 6; ++kt)
        #pragma unroll
        for (int j = 0; j < 6; ++j)
            Bres[kt * 6 + j] = Bf8[(kt * 48 + 8 * j + w) * 64 + lane];

    const int u0 = 16 * w + m;
    const int u1 = 128 + u0;
    const float br0 = bih[u0] + bhh[u0],             br1 = bih[u1] + bhh[u1];
    const float bz0 = bih[256 + u0] + bhh[256 + u0], bz1 = bih[256 + u1] + bhh[256 + u1];
    const float bnx0 = bih[512 + u0], bnx1 = bih[512 + u1];
    const float bnh0 = bhh[512 + u0], bnh1 = bhh[512 + u1];

    float4v hreg0 = {0.f, 0.f, 0.f, 0.f}, hreg1 = {0.f, 0.f, 0.f, 0.f};

    // fused-reduction accumulators: half0 -> (r = tid>>6, c), half1 -> (r+8, c)
    float mxA = -1e30f, mnA = 1e30f, smA = 0.f;
    float mxB = -1e30f, mnB = 1e30f, smB = 0.f;

    {
        #pragma unroll
        for (int half = 0; half < 2; ++half) {
            int i = tid + half * 512;
            int r = i >> 6, c = i & 63;
            int s = sblock + r, b = s >> 6, qq = s & 63;
            int p = perms[r * 64 + 0];
            int src = sd2 ? ((b * 64 + p) * 64 + qq) * 64 + c
                          : ((b * 64 + qq) * 64 + p) * 64 + c;
            float v = states[src];
            if (half == 0) { mxA = fmaxf(mxA, v); mnA = fminf(mnA, v); smA += v; }
            else           { mxB = fmaxf(mxB, v); mnB = fminf(mnB, v); smB += v; }
            xA[0][r * PADX + c] = f2bf(v);
        }
    }
    __syncthreads();

    for (int t = 0; t < 64; ++t) {
        const short* hAc = hA[t & 1];
        const short* xAc = xA[t & 1];

        float xg0 = 0.f, xg1 = 0.f;
        int w0 = -1, w1 = -1;
        if (t + 1 < 64) {
            #pragma unroll
            for (int half = 0; half < 2; ++half) {
                int i = tid + half * 512;
                int r = i >> 6, c = i & 63;
                int s = sblock + r, b = s >> 6, qq = s & 63;
                int p = perms[r * 64 + t + 1];
                int src = sd2 ? ((b * 64 + p) * 64 + qq) * 64 + c
                              : ((b * 64 + qq) * 64 + p) * 64 + c;
                float v = states[src];
                if (half == 0) {
                    xg0 = v; w0 = r * PADX + c;
                    mxA = fmaxf(mxA, v); mnA = fminf(mnA, v); smA += v;
                } else {
                    xg1 = v; w1 = r * PADX + c;
                    mxB = fmaxf(mxB, v); mnB = fminf(mnB, v); smB += v;
                }
            }
        }

        // ---- G1: R gate (kt0-5 Bres, kt6-7 Blds, kt8-9 Bx) ----
        float4v aR0 = {br0, br0, br0, br0}, aR1 = {br1, br1, br1, br1};
        #pragma unroll
        for (int kt = 0; kt < 6; ++kt) {
            short8 a = *(const short8*)(hAc + m * PADA + kt * 32 + q * 8);
            aR0 = MFMA(a, Bres[kt * 6 + 0], aR0, 0, 0, 0);
            aR1 = MFMA(a, Bres[kt * 6 + 1], aR1, 0, 0, 0);
        }
        #pragma unroll
        for (int kt = 0; kt < 2; ++kt) {
            short8 a = *(const short8*)(hAc + m * PADA + (6 + kt) * 32 + q * 8);
            aR0 = MFMA(a, Blds[(kt * 48 + 8 * 0 + w) * 64 + lane], aR0, 0, 0, 0);
            aR1 = MFMA(a, Blds[(kt * 48 + 8 * 1 + w) * 64 + lane], aR1, 0, 0, 0);
        }
        #pragma unroll
        for (int kt = 0; kt < 2; ++kt) {
            short8 a = *(const short8*)(xAc + m * PADX + kt * 32 + q * 8);
            aR0 = MFMA(a, Bf8[((8 + kt) * 48 + 8 * 0 + w) * 64 + lane], aR0, 0, 0, 0);
            aR1 = MFMA(a, Bf8[((8 + kt) * 48 + 8 * 1 + w) * 64 + lane], aR1, 0, 0, 0);
        }
        asm volatile("" ::: "memory");   // group boundary: force hA re-read

        // ---- G2: Z gate ----
        float4v aZ0 = {bz0, bz0, bz0, bz0}, aZ1 = {bz1, bz1, bz1, bz1};
        #pragma unroll
        for (int kt = 0; kt < 6; ++kt) {
            short8 a = *(const short8*)(hAc + m * PADA + kt * 32 + q * 8);
            aZ0 = MFMA(a, Bres[kt * 6 + 2], aZ0, 0, 0, 0);
            aZ1 = MFMA(a, Bres[kt * 6 + 3], aZ1, 0, 0, 0);
        }
        #pragma unroll
        for (int kt = 0; kt < 2; ++kt) {
            short8 a = *(const short8*)(hAc + m * PADA + (6 + kt) * 32 + q * 8);
            aZ0 = MFMA(a, Blds[(kt * 48 + 8 * 2 + w) * 64 + lane], aZ0, 0, 0, 0);
            aZ1 = MFMA(a, Blds[(kt * 48 + 8 * 3 + w) * 64 + lane], aZ1, 0, 0, 0);
        }
        #pragma unroll
        for (int kt = 0; kt < 2; ++kt) {
            short8 a = *(const short8*)(xAc + m * PADX + kt * 32 + q * 8);
            aZ0 = MFMA(a, Bf8[((8 + kt) * 48 + 8 * 2 + w) * 64 + lane], aZ0, 0, 0, 0);
            aZ1 = MFMA(a, Bf8[((8 + kt) * 48 + 8 * 3 + w) * 64 + lane], aZ1, 0, 0, 0);
        }
        asm volatile("" ::: "memory");   // group boundary

        // r,z sigmoids: overlap G3's MFMA issue on the VALU/trans pipe
        float r0[4], r1[4], z0[4], z1[4];
        #pragma unroll
        for (int p = 0; p < 4; ++p) {
            r0[p] = sigmoid_f(aR0[p]);
            r1[p] = sigmoid_f(aR1[p]);
            z0[p] = sigmoid_f(aZ0[p]);
            z1[p] = sigmoid_f(aZ1[p]);
        }

        // ---- G3: N gate (h-part -> aNh, x-part -> aNx) ----
        float4v aNh0 = {bnh0, bnh0, bnh0, bnh0}, aNh1 = {bnh1, bnh1, bnh1, bnh1};
        float4v aNx0 = {bnx0, bnx0, bnx0, bnx0}, aNx1 = {bnx1, bnx1, bnx1, bnx1};
        #pragma unroll
        for (int kt = 0; kt < 6; ++kt) {
            short8 a = *(const short8*)(hAc + m * PADA + kt * 32 + q * 8);
            aNh0 = MFMA(a, Bres[kt * 6 + 4], aNh0, 0, 0, 0);
            aNh1 = MFMA(a, Bres[kt * 6 + 5], aNh1, 0, 0, 0);
        }
        #pragma unroll
        for (int kt = 0; kt < 2; ++kt) {
            short8 a = *(const short8*)(hAc + m * PADA + (6 + kt) * 32 + q * 8);
            aNh0 = MFMA(a, Blds[(kt * 48 + 8 * 4 + w) * 64 + lane], aNh0, 0, 0, 0);
            aNh1 = MFMA(a, Blds[(kt * 48 + 8 * 5 + w) * 64 + lane], aNh1, 0, 0, 0);
        }
        #pragma unroll
        for (int kt = 0; kt < 2; ++kt) {
            short8 a = *(const short8*)(xAc + m * PADX + kt * 32 + q * 8);
            aNx0 = MFMA(a, Bf8[((8 + kt) * 48 + 8 * 4 + w) * 64 + lane], aNx0, 0, 0, 0);
            aNx1 = MFMA(a, Bf8[((8 + kt) * 48 + 8 * 5 + w) * 64 + lane], aNx1, 0, 0, 0);
        }

        short* hAn = hA[(t + 1) & 1];
        #pragma unroll
        for (int p = 0; p < 4; ++p) {
            int row = q * 4 + p;
            float n0 = tanh_fast(aNx0[p] + r0[p] * aNh0[p]);
            float h0 = n0 + z0[p] * (hreg0[p] - n0);
            hreg0[p] = h0;
            hAn[row * PADA + u0] = f2bf(h0);
            float n1 = tanh_fast(aNx1[p] + r1[p] * aNh1[p]);
            float h1 = n1 + z1[p] * (hreg1[p] - n1);
            hreg1[p] = h1;
            hAn[row * PADA + u1] = f2bf(h1);
        }
        if (t + 1 < 64) {
            xA[(t + 1) & 1][w0] = f2bf(xg0);
            xA[(t + 1) & 1][w1] = f2bf(xg1);
        }
        __syncthreads();
    }

    // fused-reduction writes (fp32 f + bf16 fbf)
    {
        const int off2 = sd2 ? 16 : 208;
        int r0 = tid >> 6, c0 = tid & 63;
        float smAm = smA * (1.f / 64.f);
        float smBm = smB * (1.f / 64.f);
        float* fr0 = f + (size_t)(sblock + r0) * INTER_ + off2 + c0;
        short* fb0 = fbf + (size_t)(sblock + r0) * KP_ + off2 + c0;
        fr0[0]   = mxA;   fb0[0]   = f2bf(mxA);
        fr0[64]  = smAm;  fb0[64]  = f2bf(smAm);
        fr0[128] = mnA;   fb0[128] = f2bf(mnA);
        float* fr1 = f + (size_t)(sblock + r0 + 8) * INTER_ + off2 + c0;
        short* fb1 = fbf + (size_t)(sblock + r0 + 8) * KP_ + off2 + c0;
        fr1[0]   = mxB;   fb1[0]   = f2bf(mxB);
        fr1[64]  = smBm;  fb1[64]  = f2bf(smBm);
        fr1[128] = mnB;   fb1[128] = f2bf(mnB);
    }

    const int off = sd2 ? 656 : 400;
    #pragma unroll
    for (int p = 0; p < 4; ++p) {
        int s = sblock + q * 4 + p;
        f[s * INTER_ + off + u0] = hreg0[p];
        f[s * INTER_ + off + u1] = hreg1[p];
        fbf[s * KP_ + off + u0] = f2bf(hreg0[p]);
        fbf[s * KP_ + off + u1] = f2bf(hreg1[p]);
    }
}

// ---------------------------------------------------------------------------
// xw1 = fbf[2048][928] @ Wih1^T (+bih1), bf16 MFMA. Output TRANSPOSED to
// [t][seq][768] so gru1d's per-step reads are step-contiguous.
// ---------------------------------------------------------------------------
__global__ __launch_bounds__(256) void gemm_xw1_mfma(
        const short* __restrict__ fbf, const short* __restrict__ BfragW,
        const float* __restrict__ bih, float* __restrict__ xw) {
    const int tid = threadIdx.x;
    const int lane = tid & 63;
    const int w = tid >> 6;
    const int m = lane & 15;
    const int q = lane >> 4;
    const int tn = blockIdx.x;
    const int tm = blockIdx.y;
    const int rowb = tm * 64 + w * 16;
    const short8* Bf8 = (const short8*)BfragW;

    float4v acc[4];
    #pragma unroll
    for (int nn = 0; nn < 4; ++nn) {
        float b = bih[tn * 64 + nn * 16 + m];
        acc[nn][0] = b; acc[nn][1] = b; acc[nn][2] = b; acc[nn][3] = b;
    }

    const short* arow = fbf + (rowb + m) * KP_;
    short8 a_cur = *(const short8*)(arow + q * 8);
    short8 b_cur[4];
    #pragma unroll
    for (int nn = 0; nn < 4; ++nn)
        b_cur[nn] = Bf8[(tn * 4 + nn) * 64 + lane];

    for (int kt = 0; kt < 29; ++kt) {
        short8 a_nxt = a_cur;
        short8 b_nxt[4];
        if (kt + 1 < 29) {
            a_nxt = *(const short8*)(arow + (kt + 1) * 32 + q * 8);
            #pragma unroll
            for (int nn = 0; nn < 4; ++nn)
                b_nxt[nn] = Bf8[((kt + 1) * 48 + tn * 4 + nn) * 64 + lane];
        }
        #pragma unroll
        for (int nn = 0; nn < 4; ++nn)
            acc[nn] = MFMA(a_cur, b_cur[nn], acc[nn], 0, 0, 0);
        a_cur = a_nxt;
        #pragma unroll
        for (int nn = 0; nn < 4; ++nn) b_cur[nn] = b_nxt[nn];
    }

    #pragma unroll
    for (int p = 0; p < 4; ++p) {
        int row = rowb + q * 4 + p;
        int seq = row >> 6, t = row & 63;
        #pragma unroll
        for (int nn = 0; nn < 4; ++nn)
            xw[(t * 32 + seq) * G3_ + tn * 64 + nn * 16 + m] = acc[nn][p];
    }
}

// ---------------------------------------------------------------------------
// fused: blocks 0-1 = gru1d (2 CUs); blocks 2-33 = f-reductions for tail.
// gru1d gate-grouped (R11-proven): R -> Z -> {r-sig} -> N -> {z-sig, update}.
// ---------------------------------------------------------------------------
__global__ __launch_bounds__(512, 1) void gru1d_freduce(
        const float* __restrict__ xw, const short* __restrict__ Bfrag1,
        const float* __restrict__ bhh, float* __restrict__ hlast,
        const float* __restrict__ f, float* __restrict__ g) {
    __shared__ short hA[2][16 * PADA];
    __shared__ short8 Blds[2 * 48 * 64];   // kt 6,7

    const int tid = threadIdx.x;

    if (blockIdx.x >= 2) {
        const int b = blockIdx.x - 2;
        for (int i = tid; i < INTER_; i += 512) {
            const float* fp = f + (size_t)(b * 64) * INTER_ + i;
            float mx = -1e30f, mn = 1e30f, sm = 0.f;
            #pragma unroll 8
            for (int t = 0; t < 64; ++t) {
                float v = __builtin_nontemporal_load(fp + t * INTER_);
                mx = fmaxf(mx, v); mn = fminf(mn, v); sm += v;
            }
            g[b * GRED_ + i] = mx;
            g[b * GRED_ + INTER_ + i] = sm * (1.f / 64.f);
            g[b * GRED_ + 2 * INTER_ + i] = mn;
        }
        return;
    }

    const int lane = tid & 63;
    const int w = tid >> 6;
    const int m = lane & 15;
    const int q = lane >> 4;
    const int sblock = blockIdx.x * 16;

    for (int i = tid; i < 16 * PADA; i += 512) hA[0][i] = 0;
    {
        const uint4* src = (const uint4*)(Bfrag1 + 6 * 48 * 64 * 8);
        uint4* dst = (uint4*)Blds;
        #pragma unroll
        for (int rep = 0; rep < 12; ++rep)
            dst[tid + rep * 512] = src[tid + rep * 512];
    }
    const short8* Bf8 = (const short8*)Bfrag1;
    short8 Bres[36];
    #pragma unroll
    for (int kt = 0; kt < 6; ++kt)
        #pragma unroll
        for (int j = 0; j < 6; ++j)
            Bres[kt * 6 + j] = Bf8[(kt * 48 + 8 * j + w) * 64 + lane];

    const int u0 = 16 * w + m;
    const int u1 = 128 + u0;
    const float br0 = bhh[u0],       br1 = bhh[u1];
    const float bz0 = bhh[256 + u0], bz1 = bhh[256 + u1];
    const float bn0 = bhh[512 + u0], bn1 = bhh[512 + u1];

    float4v hreg0 = {0.f, 0.f, 0.f, 0.f}, hreg1 = {0.f, 0.f, 0.f, 0.f};
    __syncthreads();

    for (int t = 0; t < 64; ++t) {
        const short* hAc = hA[t & 1];

        float giR0[4], giR1[4], giZ0[4], giZ1[4], giN0[4], giN1[4];
        #pragma unroll
        for (int p = 0; p < 4; ++p) {
            const float* gr = xw + (size_t)(t * 32 + sblock + q * 4 + p) * G3_;
            giR0[p] = gr[u0];        giR1[p] = gr[u1];
            giZ0[p] = gr[256 + u0];  giZ1[p] = gr[256 + u1];
            giN0[p] = gr[512 + u0];  giN1[p] = gr[512 + u1];
        }

        // ---- R group (16 MFMAs) ----
        float4v aR0 = {br0, br0, br0, br0}, aR1 = {br1, br1, br1, br1};
        #pragma unroll
        for (int kt = 0; kt < 6; ++kt) {
            short8 a = *(const short8*)(hAc + m * PADA + kt * 32 + q * 8);
            aR0 = MFMA(a, Bres[kt * 6 + 0], aR0, 0, 0, 0);
            aR1 = MFMA(a, Bres[kt * 6 + 1], aR1, 0, 0, 0);
        }
        #pragma unroll
        for (int kt = 0; kt < 2; ++kt) {
            short8 a = *(const short8*)(hAc + m * PADA + (6 + kt) * 32 + q * 8);
            aR0 = MFMA(a, Blds[(kt * 48 + 8 * 0 + w) * 64 + lane], aR0, 0, 0, 0);
            aR1 = MFMA(a, Blds[(kt * 48 + 8 * 1 + w) * 64 + lane], aR1, 0, 0, 0);
        }

        // ---- Z group (16 MFMAs) ----
        float4v aZ0 = {bz0, bz0, bz0, bz0}, aZ1 = {bz1, bz1, bz1, bz1};
        #pragma unroll
        for (int kt = 0; kt < 6; ++kt) {
            short8 a = *(const short8*)(hAc + m * PADA + kt * 32 + q * 8);
            aZ0 = MFMA(a, Bres[kt * 6 + 2], aZ0, 0, 0, 0);
            aZ1 = MFMA(a, Bres[kt * 6 + 3], aZ1, 0, 0, 0);
        }
        #pragma unroll
        for (int kt = 0; kt < 2; ++kt) {
            short8 a = *(const short8*)(hAc + m * PADA + (6 + kt) * 32 + q * 8);
            aZ0 = MFMA(a, Blds[(kt * 48 + 8 * 2 + w) * 64 + lane], aZ0, 0, 0, 0);
            aZ1 = MFMA(a, Blds[(kt * 48 + 8 * 3 + w) * 64 + lane], aZ1, 0, 0, 0);
        }

        // r-sigmoids: VALU runs while N-group MFMAs occupy the matrix pipe
        float r0[4], r1[4];
        #pragma unroll
        for (int p = 0; p < 4; ++p) {
            r0[p] = sigmoid_f(giR0[p] + aR0[p]);
            r1[p] = sigmoid_f(giR1[p] + aR1[p]);
        }

        // ---- N group (16 MFMAs) ----
        float4v aN0 = {bn0, bn0, bn0, bn0}, aN1 = {bn1, bn1, bn1, bn1};
        #pragma unroll
        for (int kt = 0; kt < 6; ++kt) {
            short8 a = *(const short8*)(hAc + m * PADA + kt * 32 + q * 8);
            aN0 = MFMA(a, Bres[kt * 6 + 4], aN0, 0, 0, 0);
            aN1 = MFMA(a, Bres[kt * 6 + 5], aN1, 0, 0, 0);
        }
        #pragma unroll
        for (int kt = 0; kt < 2; ++kt) {
            short8 a = *(const short8*)(hAc + m * PADA + (6 + kt) * 32 + q * 8);
            aN0 = MFMA(a, Blds[(kt * 48 + 8 * 4 + w) * 64 + lane], aN0, 0, 0, 0);
            aN1 = MFMA(a, Blds[(kt * 48 + 8 * 5 + w) * 64 + lane], aN1, 0, 0, 0);
        }

        // z-sigmoids overlap the N-group MFMAs
        float z0[4], z1[4];
        #pragma unroll
        for (int p = 0; p < 4; ++p) {
            z0[p] = sigmoid_f(giZ0[p] + aZ0[p]);
            z1[p] = sigmoid_f(giZ1[p] + aZ1[p]);
        }

        short* hAn = hA[(t + 1) & 1];
        #pragma unroll
        for (int p = 0; p < 4; ++p) {
            int row = q * 4 + p;
            float n0 = tanh_fast(giN0[p] + r0[p] * aN0[p]);
            float h0 = n0 + z0[p] * (hreg0[p] - n0);
            hreg0[p] = h0;
            hAn[row * PADA + u0] = f2bf(h0);
            float n1 = tanh_fast(giN1[p] + r1[p] * aN1[p]);
            float h1 = n1 + z1[p] * (hreg1[p] - n1);
            hreg1[p] = h1;
            hAn[row * PADA + u1] = f2bf(h1);
        }
        __syncthreads();
    }

    #pragma unroll
    for (int p = 0; p < 4; ++p) {
        int s = sblock + q * 4 + p;
        hlast[s * 256 + u0] = hreg0[p];
        hlast[s * 256 + u1] = hreg1[p];
    }
}

// ---------------------------------------------------------------------------
// tail_fc: g_lds = [g(b) | hlast(b)], fc1+relu, fc2
// ---------------------------------------------------------------------------
__global__ __launch_bounds__(256) void tail_fc(
        const float* __restrict__ g, const float* __restrict__ hlast,
        const float* __restrict__ fc1Wt, const float* __restrict__ fc1b,
        const float* __restrict__ fc2W, const float* __restrict__ fc2b,
        float* __restrict__ out) {
    __shared__ float g_lds[FCIN_];
    __shared__ float red[4];
    const int tid = threadIdx.x;
    const int b = blockIdx.x;
    for (int i = tid; i < GRED_; i += 256) g_lds[i] = g[b * GRED_ + i];
    g_lds[GRED_ + tid] = hlast[b * 256 + tid];
    __syncthreads();

    float a0 = 0.f, a1 = 0.f, a2 = 0.f, a3 = 0.f;
    for (int i = 0; i < FCIN_; i += 4) {
        a0 = fmaf(g_lds[i],     fc1Wt[(i) * 256 + tid],     a0);
        a1 = fmaf(g_lds[i + 1], fc1Wt[(i + 1) * 256 + tid], a1);
        a2 = fmaf(g_lds[i + 2], fc1Wt[(i + 2) * 256 + tid], a2);
        a3 = fmaf(g_lds[i + 3], fc1Wt[(i + 3) * 256 + tid], a3);
    }
    float acc = ((a0 + a1) + (a2 + a3)) + fc1b[tid];
    float hv = fmaxf(acc, 0.f);
    float part = hv * fc2W[tid];
    #pragma unroll
    for (int off = 32; off >= 1; off >>= 1)
        part += __shfl_down(part, off, 64);
    if ((tid & 63) == 0) red[tid >> 6] = part;
    __syncthreads();
    if (tid == 0)
        out[b] = fc2b[0] + red[0] + red[1] + red[2] + red[3];
}

// ---------------------------------------------------------------------------
extern "C" void kernel_launch(void* const* d_in, const int* in_sizes, int n_in,
                              void* d_out, int out_size, void* d_ws, size_t ws_size,
                              hipStream_t stream) {
    const float* x1     = (const float*)d_in[0];
    const float* states = (const float*)d_in[1];
    const int*   perm1  = (const int*)d_in[2];
    const int*   perm2  = (const int*)d_in[3];
    const float* Wih2   = (const float*)d_in[4];
    const float* Whh2   = (const float*)d_in[5];
    const float* bih2   = (const float*)d_in[6];
    const float* bhh2   = (const float*)d_in[7];
    const float* Wih1   = (const float*)d_in[8];
    const float* Whh1   = (const float*)d_in[9];
    const float* bih1   = (const float*)d_in[10];
    const float* bhh1   = (const float*)d_in[11];
    const float* fc1W   = (const float*)d_in[12];
    const float* fc1b   = (const float*)d_in[13];
    const float* fc2W   = (const float*)d_in[14];
    const float* fc2b   = (const float*)d_in[15];
    float* out = (float*)d_out;

    float* ws = (float*)d_ws;
    short* Bfrag   = (short*)ws;                          // 245760 bf16
    short* Bfrag1  = (short*)(ws + 122880);               // 196608 bf16
    short* Bfrag1W = (short*)(ws + 122880 + 98304);       // 712704 bf16
    float* fc1Wt   = ws + 577536;                         // 765952 f
    float* f       = fc1Wt + FCIN_ * 256;                 // 1343488
    short* fbf     = (short*)(f + 2048 * INTER_);         // 1900544 bf16
    float* xw1     = f + 2048 * INTER_ + 950272;          // 4161536
    float* hlast   = xw1 + 2048 * G3_;                    // 5734400
    float* g       = hlast + 8192;                        // 5742592 (+87552)

    prep_kernel<<<dim3(2992), 256, 0, stream>>>(Whh2, Wih2, Whh1, Wih1, fc1W,
                                                x1, Bfrag, Bfrag1, Bfrag1W,
                                                fc1Wt, f, fbf);
    gru2d_mfma<<<dim3(256), 512, 0, stream>>>(states, perm1, perm2, Bfrag,
                                              bih2, bhh2, f, fbf);
    gemm_xw1_mfma<<<dim3(12, 32), 256, 0, stream>>>(fbf, Bfrag1W, bih1, xw1);
    gru1d_freduce<<<dim3(34), 512, 0, stream>>>(xw1, Bfrag1, bhh1, hlast, f, g);
    tail_fc<<<dim3(32), 256, 0, stream>>>(g, hlast, fc1Wt, fc1b, fc2W, fc2b, out);
}

// Round 13
// 626.062 us; speedup vs baseline: 1.0306x; 1.0306x over previous
//
#include <hip/hip_runtime.h>
#include <cmath>

#define B_ 32
#define N_ 64
#define H_ 256
#define G3_ 768           // 3*H
#define INTER_ 912        // 2H + 6C + C1
#define KP_ 928           // INTER_ padded to 29*32 for bf16 MFMA GEMM
#define FCIN_ 2992        // 3*INTER + H
#define GRED_ 2736        // 3*INTER (f reductions part of g)

#define PADA 264          // hA row stride (bf16 elems)
#define PADX 72           // xA row stride (bf16 elems)

typedef __attribute__((ext_vector_type(8))) short short8;
typedef __attribute__((ext_vector_type(4))) short sshort4;
typedef __attribute__((ext_vector_type(4))) float float4v;

#define MFMA __builtin_amdgcn_mfma_f32_16x16x32_bf16

// single-instruction transcendentals: v_exp_f32 is exp2, v_rcp_f32
__device__ __forceinline__ float sigmoid_f(float x) {
    return __builtin_amdgcn_rcpf(1.0f + __builtin_amdgcn_exp2f(-1.44269504f * x));
}
__device__ __forceinline__ float tanh_fast(float x) {
    return 1.0f - 2.0f * __builtin_amdgcn_rcpf(1.0f + __builtin_amdgcn_exp2f(2.88539008f * x));
}
__device__ __forceinline__ unsigned f2bf_bits(float x) {
    unsigned u = __float_as_uint(x);
    return (u + 0x7fffu + ((u >> 16) & 1u)) >> 16;
}
__device__ __forceinline__ short f2bf(float x) { return (short)f2bf_bits(x); }

// ---------------------------------------------------------------------------
// prep: (a) Bfrag   = gru2d weights, fragment-major bf16 (layout verified R2)
//       (b) Bfrag1  = gru1d Whh, same pack (8 kt)
//       (c) Bfrag1W = gru1d Wih (768 x 912), same pack, K zero-padded to 928
//       (d) fc1Wt transpose
//       (e) x1 copy -> f[:, 0:16] AND fbf[:, 0:16] (bf16), + fbf K-pad
// Fragment layout: [kt][ntile(48)][lane(64)][j(8)] bf16; value = W[n][k] with
// n = ntile*16 + (lane&15), k = kt*32 + (lane>>4)*8 + j.
// ---------------------------------------------------------------------------
__global__ __launch_bounds__(256) void prep_kernel(
        const float* __restrict__ Whh2, const float* __restrict__ Wih2,
        const float* __restrict__ Whh1, const float* __restrict__ Wih1,
        const float* __restrict__ fc1W, const float* __restrict__ x1,
        short* __restrict__ Bfrag, short* __restrict__ Bfrag1,
        short* __restrict__ Bfrag1W, float* __restrict__ fc1Wt,
        float* __restrict__ f, short* __restrict__ fbf) {
    int idx = blockIdx.x * 256 + threadIdx.x;
    if (idx < 10 * 48 * 64 * 8) {
        int j = idx & 7, lane = (idx >> 3) & 63, tile = idx >> 9;
        int nt = tile % 48, kt = tile / 48;
        int n = nt * 16 + (lane & 15);
        int kb = (lane >> 4) * 8 + j;
        float v = (kt < 8) ? Whh2[n * 256 + kt * 32 + kb]
                           : Wih2[n * 64 + (kt - 8) * 32 + kb];
        Bfrag[idx] = f2bf(v);
    }
    if (idx < 8 * 48 * 64 * 8) {
        int j = idx & 7, lane = (idx >> 3) & 63, tile = idx >> 9;
        int nt = tile % 48, kt = tile / 48;
        int n = nt * 16 + (lane & 15);
        int k = kt * 32 + (lane >> 4) * 8 + j;
        Bfrag1[idx] = f2bf(Whh1[n * 256 + k]);
    }
    if (idx < 29 * 48 * 64 * 8) {
        int j = idx & 7, lane = (idx >> 3) & 63, tile = idx >> 9;
        int nt = tile % 48, kt = tile / 48;
        int n = nt * 16 + (lane & 15);
        int k = kt * 32 + (lane >> 4) * 8 + j;
        Bfrag1W[idx] = (k < INTER_) ? f2bf(Wih1[n * INTER_ + k]) : (short)0;
    }
    if (idx < FCIN_ * 256) {
        int o = idx & 255, i = idx >> 8;
        fc1Wt[idx] = fc1W[o * FCIN_ + i];
    }
    if (idx < 2048 * 16) {
        int bj = idx >> 4, c = idx & 15;
        float v = x1[idx];
        f[bj * INTER_ + c] = v;
        fbf[bj * KP_ + c] = f2bf(v);
        fbf[bj * KP_ + 912 + c] = 0;   // zero-pad K 912..927
    }
}

// ---------------------------------------------------------------------------
// gru2d (R11-best, restored): 512 thr, xA staging, per-step Bx reload, hA
// double-buffer, single barrier/step, bias-folded init, fused d[]
// reductions, direct fbf (bf16) epilogue writes. Interleaved 6-chain MFMA:
// single pass over hA per step (8 ds_read_b128) — R12's gate-grouped variant
// tripled LDS reads and bank conflicts (5.2M -> 15.7M) and regressed.
// ---------------------------------------------------------------------------
__global__ __launch_bounds__(512, 1) void gru2d_mfma(
        const float* __restrict__ states,
        const int* __restrict__ perm1, const int* __restrict__ perm2,
        const short* __restrict__ Bfrag,
        const float* __restrict__ bih, const float* __restrict__ bhh,
        float* __restrict__ f, short* __restrict__ fbf) {
    __shared__ short hA[2][16 * PADA];
    __shared__ short xA[2][16 * PADX];
    __shared__ short8 Blds[2 * 48 * 64];
    __shared__ int perms[1024];

    const int tid = threadIdx.x;
    const int lane = tid & 63;
    const int w = tid >> 6;
    const int m = lane & 15;
    const int q = lane >> 4;
    const bool sd2 = blockIdx.x >= 128;
    const int sblock = (blockIdx.x & 127) * 16;

    for (int i = tid; i < 1024; i += 512) {
        int r = i >> 6, t = i & 63;
        int qq = (sblock + r) & 63;
        perms[i] = sd2 ? perm2[qq * 64 + t] : perm1[qq * 64 + t];
    }
    for (int i = tid; i < 16 * PADA; i += 512) hA[0][i] = 0;
    {
        const uint4* src = (const uint4*)(Bfrag + 6 * 48 * 64 * 8);
        uint4* dst = (uint4*)Blds;
        #pragma unroll
        for (int rep = 0; rep < 12; ++rep)
            dst[tid + rep * 512] = src[tid + rep * 512];
    }

    const short8* Bf8 = (const short8*)Bfrag;
    short8 Bres[36];
    #pragma unroll
    for (int kt = 0; kt < 6; ++kt)
        #pragma unroll
        for (int j = 0; j < 6; ++j)
            Bres[kt * 6 + j] = Bf8[(kt * 48 + 8 * j + w) * 64 + lane];

    const int u0 = 16 * w + m;
    const int u1 = 128 + u0;
    const float br0 = bih[u0] + bhh[u0],             br1 = bih[u1] + bhh[u1];
    const float bz0 = bih[256 + u0] + bhh[256 + u0], bz1 = bih[256 + u1] + bhh[256 + u1];
    const float bnx0 = bih[512 + u0], bnx1 = bih[512 + u1];
    const float bnh0 = bhh[512 + u0], bnh1 = bhh[512 + u1];

    float4v hreg0 = {0.f, 0.f, 0.f, 0.f}, hreg1 = {0.f, 0.f, 0.f, 0.f};

    // fused-reduction accumulators: half0 -> (r = tid>>6, c), half1 -> (r+8, c)
    float mxA = -1e30f, mnA = 1e30f, smA = 0.f;
    float mxB = -1e30f, mnB = 1e30f, smB = 0.f;

    {
        #pragma unroll
        for (int half = 0; half < 2; ++half) {
            int i = tid + half * 512;
            int r = i >> 6, c = i & 63;
            int s = sblock + r, b = s >> 6, qq = s & 63;
            int p = perms[r * 64 + 0];
            int src = sd2 ? ((b * 64 + p) * 64 + qq) * 64 + c
                          : ((b * 64 + qq) * 64 + p) * 64 + c;
            float v = states[src];
            if (half == 0) { mxA = fmaxf(mxA, v); mnA = fminf(mnA, v); smA += v; }
            else           { mxB = fmaxf(mxB, v); mnB = fminf(mnB, v); smB += v; }
            xA[0][r * PADX + c] = f2bf(v);
        }
    }
    __syncthreads();

    for (int t = 0; t < 64; ++t) {
        const short* hAc = hA[t & 1];
        const short* xAc = xA[t & 1];

        short8 Bx[12];
        #pragma unroll
        for (int kt = 0; kt < 2; ++kt)
            #pragma unroll
            for (int j = 0; j < 6; ++j)
                Bx[kt * 6 + j] = Bf8[((8 + kt) * 48 + 8 * j + w) * 64 + lane];

        float xg0 = 0.f, xg1 = 0.f;
        int w0 = -1, w1 = -1;
        if (t + 1 < 64) {
            #pragma unroll
            for (int half = 0; half < 2; ++half) {
                int i = tid + half * 512;
                int r = i >> 6, c = i & 63;
                int s = sblock + r, b = s >> 6, qq = s & 63;
                int p = perms[r * 64 + t + 1];
                int src = sd2 ? ((b * 64 + p) * 64 + qq) * 64 + c
                              : ((b * 64 + qq) * 64 + p) * 64 + c;
                float v = states[src];
                if (half == 0) {
                    xg0 = v; w0 = r * PADX + c;
                    mxA = fmaxf(mxA, v); mnA = fminf(mnA, v); smA += v;
                } else {
                    xg1 = v; w1 = r * PADX + c;
                    mxB = fmaxf(mxB, v); mnB = fminf(mnB, v); smB += v;
                }
            }
        }

        // ---- interleaved 6-chain MFMA, biases pre-folded ----
        float4v aR0 = {br0, br0, br0, br0},     aR1 = {br1, br1, br1, br1};
        float4v aZ0 = {bz0, bz0, bz0, bz0},     aZ1 = {bz1, bz1, bz1, bz1};
        float4v aNh0 = {bnh0, bnh0, bnh0, bnh0}, aNh1 = {bnh1, bnh1, bnh1, bnh1};
        float4v aNx0 = {bnx0, bnx0, bnx0, bnx0}, aNx1 = {bnx1, bnx1, bnx1, bnx1};

        #pragma unroll
        for (int kt = 0; kt < 6; ++kt) {
            short8 a = *(const short8*)(hAc + m * PADA + kt * 32 + q * 8);
            aR0  = MFMA(a, Bres[kt * 6 + 0], aR0, 0, 0, 0);
            aR1  = MFMA(a, Bres[kt * 6 + 1], aR1, 0, 0, 0);
            aZ0  = MFMA(a, Bres[kt * 6 + 2], aZ0, 0, 0, 0);
            aZ1  = MFMA(a, Bres[kt * 6 + 3], aZ1, 0, 0, 0);
            aNh0 = MFMA(a, Bres[kt * 6 + 4], aNh0, 0, 0, 0);
            aNh1 = MFMA(a, Bres[kt * 6 + 5], aNh1, 0, 0, 0);
        }
        #pragma unroll
        for (int kt = 0; kt < 2; ++kt) {
            short8 a = *(const short8*)(hAc + m * PADA + (6 + kt) * 32 + q * 8);
            short8 b0 = Blds[(kt * 48 + 8 * 0 + w) * 64 + lane];
            short8 b1 = Blds[(kt * 48 + 8 * 1 + w) * 64 + lane];
            short8 b2 = Blds[(kt * 48 + 8 * 2 + w) * 64 + lane];
            short8 b3 = Blds[(kt * 48 + 8 * 3 + w) * 64 + lane];
            short8 b4 = Blds[(kt * 48 + 8 * 4 + w) * 64 + lane];
            short8 b5 = Blds[(kt * 48 + 8 * 5 + w) * 64 + lane];
            aR0  = MFMA(a, b0, aR0, 0, 0, 0);
            aR1  = MFMA(a, b1, aR1, 0, 0, 0);
            aZ0  = MFMA(a, b2, aZ0, 0, 0, 0);
            aZ1  = MFMA(a, b3, aZ1, 0, 0, 0);
            aNh0 = MFMA(a, b4, aNh0, 0, 0, 0);
            aNh1 = MFMA(a, b5, aNh1, 0, 0, 0);
        }
        #pragma unroll
        for (int kt = 0; kt < 2; ++kt) {
            short8 a = *(const short8*)(xAc + m * PADX + kt * 32 + q * 8);
            aR0  = MFMA(a, Bx[kt * 6 + 0], aR0, 0, 0, 0);
            aR1  = MFMA(a, Bx[kt * 6 + 1], aR1, 0, 0, 0);
            aZ0  = MFMA(a, Bx[kt * 6 + 2], aZ0, 0, 0, 0);
            aZ1  = MFMA(a, Bx[kt * 6 + 3], aZ1, 0, 0, 0);
            aNx0 = MFMA(a, Bx[kt * 6 + 4], aNx0, 0, 0, 0);
            aNx1 = MFMA(a, Bx[kt * 6 + 5], aNx1, 0, 0, 0);
        }

        short* hAn = hA[(t + 1) & 1];
        #pragma unroll
        for (int p = 0; p < 4; ++p) {
            int row = q * 4 + p;
            float r0 = sigmoid_f(aR0[p]);
            float z0 = sigmoid_f(aZ0[p]);
            float n0 = tanh_fast(aNx0[p] + r0 * aNh0[p]);
            float h0 = n0 + z0 * (hreg0[p] - n0);
            hreg0[p] = h0;
            hAn[row * PADA + u0] = f2bf(h0);
            float r1 = sigmoid_f(aR1[p]);
            float z1 = sigmoid_f(aZ1[p]);
            float n1 = tanh_fast(aNx1[p] + r1 * aNh1[p]);
            float h1 = n1 + z1 * (hreg1[p] - n1);
            hreg1[p] = h1;
            hAn[row * PADA + u1] = f2bf(h1);
        }
        if (t + 1 < 64) {
            xA[(t + 1) & 1][w0] = f2bf(xg0);
            xA[(t + 1) & 1][w1] = f2bf(xg1);
        }
        __syncthreads();
    }

    // fused-reduction writes (fp32 f + bf16 fbf)
    {
        const int off2 = sd2 ? 16 : 208;
        int r0 = tid >> 6, c0 = tid & 63;
        float smAm = smA * (1.f / 64.f);
        float smBm = smB * (1.f / 64.f);
        float* fr0 = f + (size_t)(sblock + r0) * INTER_ + off2 + c0;
        short* fb0 = fbf + (size_t)(sblock + r0) * KP_ + off2 + c0;
        fr0[0]   = mxA;   fb0[0]   = f2bf(mxA);
        fr0[64]  = smAm;  fb0[64]  = f2bf(smAm);
        fr0[128] = mnA;   fb0[128] = f2bf(mnA);
        float* fr1 = f + (size_t)(sblock + r0 + 8) * INTER_ + off2 + c0;
        short* fb1 = fbf + (size_t)(sblock + r0 + 8) * KP_ + off2 + c0;
        fr1[0]   = mxB;   fb1[0]   = f2bf(mxB);
        fr1[64]  = smBm;  fb1[64]  = f2bf(smBm);
        fr1[128] = mnB;   fb1[128] = f2bf(mnB);
    }

    const int off = sd2 ? 656 : 400;
    #pragma unroll
    for (int p = 0; p < 4; ++p) {
        int s = sblock + q * 4 + p;
        f[s * INTER_ + off + u0] = hreg0[p];
        f[s * INTER_ + off + u1] = hreg1[p];
        fbf[s * KP_ + off + u0] = f2bf(hreg0[p]);
        fbf[s * KP_ + off + u1] = f2bf(hreg1[p]);
    }
}

// ---------------------------------------------------------------------------
// xw1 = fbf[2048][928] @ Wih1^T (+bih1), bf16 MFMA. Output TRANSPOSED to
// [t][seq][768] so gru1d's per-step reads are step-contiguous.
// ---------------------------------------------------------------------------
__global__ __launch_bounds__(256) void gemm_xw1_mfma(
        const short* __restrict__ fbf, const short* __restrict__ BfragW,
        const float* __restrict__ bih, float* __restrict__ xw) {
    const int tid = threadIdx.x;
    const int lane = tid & 63;
    const int w = tid >> 6;
    const int m = lane & 15;
    const int q = lane >> 4;
    const int tn = blockIdx.x;
    const int tm = blockIdx.y;
    const int rowb = tm * 64 + w * 16;
    const short8* Bf8 = (const short8*)BfragW;

    float4v acc[4];
    #pragma unroll
    for (int nn = 0; nn < 4; ++nn) {
        float b = bih[tn * 64 + nn * 16 + m];
        acc[nn][0] = b; acc[nn][1] = b; acc[nn][2] = b; acc[nn][3] = b;
    }

    const short* arow = fbf + (rowb + m) * KP_;
    short8 a_cur = *(const short8*)(arow + q * 8);
    short8 b_cur[4];
    #pragma unroll
    for (int nn = 0; nn < 4; ++nn)
        b_cur[nn] = Bf8[(tn * 4 + nn) * 64 + lane];

    for (int kt = 0; kt < 29; ++kt) {
        short8 a_nxt = a_cur;
        short8 b_nxt[4];
        if (kt + 1 < 29) {
            a_nxt = *(const short8*)(arow + (kt + 1) * 32 + q * 8);
            #pragma unroll
            for (int nn = 0; nn < 4; ++nn)
                b_nxt[nn] = Bf8[((kt + 1) * 48 + tn * 4 + nn) * 64 + lane];
        }
        #pragma unroll
        for (int nn = 0; nn < 4; ++nn)
            acc[nn] = MFMA(a_cur, b_cur[nn], acc[nn], 0, 0, 0);
        a_cur = a_nxt;
        #pragma unroll
        for (int nn = 0; nn < 4; ++nn) b_cur[nn] = b_nxt[nn];
    }

    #pragma unroll
    for (int p = 0; p < 4; ++p) {
        int row = rowb + q * 4 + p;
        int seq = row >> 6, t = row & 63;
        #pragma unroll
        for (int nn = 0; nn < 4; ++nn)
            xw[(t * 32 + seq) * G3_ + tn * 64 + nn * 16 + m] = acc[nn][p];
    }
}

// ---------------------------------------------------------------------------
// fused: blocks 0-1 = gru1d (2 CUs); blocks 2-33 = f-reductions for tail.
// gru1d gate-grouped (R11-proven): R -> Z -> {r-sig} -> N -> {z-sig, update}.
// ---------------------------------------------------------------------------
__global__ __launch_bounds__(512, 1) void gru1d_freduce(
        const float* __restrict__ xw, const short* __restrict__ Bfrag1,
        const float* __restrict__ bhh, float* __restrict__ hlast,
        const float* __restrict__ f, float* __restrict__ g) {
    __shared__ short hA[2][16 * PADA];
    __shared__ short8 Blds[2 * 48 * 64];   // kt 6,7

    const int tid = threadIdx.x;

    if (blockIdx.x >= 2) {
        const int b = blockIdx.x - 2;
        for (int i = tid; i < INTER_; i += 512) {
            const float* fp = f + (size_t)(b * 64) * INTER_ + i;
            float mx = -1e30f, mn = 1e30f, sm = 0.f;
            #pragma unroll 8
            for (int t = 0; t < 64; ++t) {
                float v = __builtin_nontemporal_load(fp + t * INTER_);
                mx = fmaxf(mx, v); mn = fminf(mn, v); sm += v;
            }
            g[b * GRED_ + i] = mx;
            g[b * GRED_ + INTER_ + i] = sm * (1.f / 64.f);
            g[b * GRED_ + 2 * INTER_ + i] = mn;
        }
        return;
    }

    const int lane = tid & 63;
    const int w = tid >> 6;
    const int m = lane & 15;
    const int q = lane >> 4;
    const int sblock = blockIdx.x * 16;

    for (int i = tid; i < 16 * PADA; i += 512) hA[0][i] = 0;
    {
        const uint4* src = (const uint4*)(Bfrag1 + 6 * 48 * 64 * 8);
        uint4* dst = (uint4*)Blds;
        #pragma unroll
        for (int rep = 0; rep < 12; ++rep)
            dst[tid + rep * 512] = src[tid + rep * 512];
    }
    const short8* Bf8 = (const short8*)Bfrag1;
    short8 Bres[36];
    #pragma unroll
    for (int kt = 0; kt < 6; ++kt)
        #pragma unroll
        for (int j = 0; j < 6; ++j)
            Bres[kt * 6 + j] = Bf8[(kt * 48 + 8 * j + w) * 64 + lane];

    const int u0 = 16 * w + m;
    const int u1 = 128 + u0;
    const float br0 = bhh[u0],       br1 = bhh[u1];
    const float bz0 = bhh[256 + u0], bz1 = bhh[256 + u1];
    const float bn0 = bhh[512 + u0], bn1 = bhh[512 + u1];

    float4v hreg0 = {0.f, 0.f, 0.f, 0.f}, hreg1 = {0.f, 0.f, 0.f, 0.f};
    __syncthreads();

    for (int t = 0; t < 64; ++t) {
        const short* hAc = hA[t & 1];

        float giR0[4], giR1[4], giZ0[4], giZ1[4], giN0[4], giN1[4];
        #pragma unroll
        for (int p = 0; p < 4; ++p) {
            const float* gr = xw + (size_t)(t * 32 + sblock + q * 4 + p) * G3_;
            giR0[p] = gr[u0];        giR1[p] = gr[u1];
            giZ0[p] = gr[256 + u0];  giZ1[p] = gr[256 + u1];
            giN0[p] = gr[512 + u0];  giN1[p] = gr[512 + u1];
        }

        // ---- R group (16 MFMAs) ----
        float4v aR0 = {br0, br0, br0, br0}, aR1 = {br1, br1, br1, br1};
        #pragma unroll
        for (int kt = 0; kt < 6; ++kt) {
            short8 a = *(const short8*)(hAc + m * PADA + kt * 32 + q * 8);
            aR0 = MFMA(a, Bres[kt * 6 + 0], aR0, 0, 0, 0);
            aR1 = MFMA(a, Bres[kt * 6 + 1], aR1, 0, 0, 0);
        }
        #pragma unroll
        for (int kt = 0; kt < 2; ++kt) {
            short8 a = *(const short8*)(hAc + m * PADA + (6 + kt) * 32 + q * 8);
            aR0 = MFMA(a, Blds[(kt * 48 + 8 * 0 + w) * 64 + lane], aR0, 0, 0, 0);
            aR1 = MFMA(a, Blds[(kt * 48 + 8 * 1 + w) * 64 + lane], aR1, 0, 0, 0);
        }

        // ---- Z group (16 MFMAs) ----
        float4v aZ0 = {bz0, bz0, bz0, bz0}, aZ1 = {bz1, bz1, bz1, bz1};
        #pragma unroll
        for (int kt = 0; kt < 6; ++kt) {
            short8 a = *(const short8*)(hAc + m * PADA + kt * 32 + q * 8);
            aZ0 = MFMA(a, Bres[kt * 6 + 2], aZ0, 0, 0, 0);
            aZ1 = MFMA(a, Bres[kt * 6 + 3], aZ1, 0, 0, 0);
        }
        #pragma unroll
        for (int kt = 0; kt < 2; ++kt) {
            short8 a = *(const short8*)(hAc + m * PADA + (6 + kt) * 32 + q * 8);
            aZ0 = MFMA(a, Blds[(kt * 48 + 8 * 2 + w) * 64 + lane], aZ0, 0, 0, 0);
            aZ1 = MFMA(a, Blds[(kt * 48 + 8 * 3 + w) * 64 + lane], aZ1, 0, 0, 0);
        }

        // r-sigmoids: VALU runs while N-group MFMAs occupy the matrix pipe
        float r0[4], r1[4];
        #pragma unroll
        for (int p = 0; p < 4; ++p) {
            r0[p] = sigmoid_f(giR0[p] + aR0[p]);
            r1[p] = sigmoid_f(giR1[p] + aR1[p]);
        }

        // ---- N group (16 MFMAs) ----
        float4v aN0 = {bn0, bn0, bn0, bn0}, aN1 = {bn1, bn1, bn1, bn1};
        #pragma unroll
        for (int kt = 0; kt < 6; ++kt) {
            short8 a = *(const short8*)(hAc + m * PADA + kt * 32 + q * 8);
            aN0 = MFMA(a, Bres[kt * 6 + 4], aN0, 0, 0, 0);
            aN1 = MFMA(a, Bres[kt * 6 + 5], aN1, 0, 0, 0);
        }
        #pragma unroll
        for (int kt = 0; kt < 2; ++kt) {
            short8 a = *(const short8*)(hAc + m * PADA + (6 + kt) * 32 + q * 8);
            aN0 = MFMA(a, Blds[(kt * 48 + 8 * 4 + w) * 64 + lane], aN0, 0, 0, 0);
            aN1 = MFMA(a, Blds[(kt * 48 + 8 * 5 + w) * 64 + lane], aN1, 0, 0, 0);
        }

        // z-sigmoids overlap the N-group MFMAs
        float z0[4], z1[4];
        #pragma unroll
        for (int p = 0; p < 4; ++p) {
            z0[p] = sigmoid_f(giZ0[p] + aZ0[p]);
            z1[p] = sigmoid_f(giZ1[p] + aZ1[p]);
        }

        short* hAn = hA[(t + 1) & 1];
        #pragma unroll
        for (int p = 0; p < 4; ++p) {
            int row = q * 4 + p;
            float n0 = tanh_fast(giN0[p] + r0[p] * aN0[p]);
            float h0 = n0 + z0[p] * (hreg0[p] - n0);
            hreg0[p] = h0;
            hAn[row * PADA + u0] = f2bf(h0);
            float n1 = tanh_fast(giN1[p] + r1[p] * aN1[p]);
            float h1 = n1 + z1[p] * (hreg1[p] - n1);
            hreg1[p] = h1;
            hAn[row * PADA + u1] = f2bf(h1);
        }
        __syncthreads();
    }

    #pragma unroll
    for (int p = 0; p < 4; ++p) {
        int s = sblock + q * 4 + p;
        hlast[s * 256 + u0] = hreg0[p];
        hlast[s * 256 + u1] = hreg1[p];
    }
}

// ---------------------------------------------------------------------------
// tail_fc: g_lds = [g(b) | hlast(b)], fc1+relu, fc2
// ---------------------------------------------------------------------------
__global__ __launch_bounds__(256) void tail_fc(
        const float* __restrict__ g, const float* __restrict__ hlast,
        const float* __restrict__ fc1Wt, const float* __restrict__ fc1b,
        const float* __restrict__ fc2W, const float* __restrict__ fc2b,
        float* __restrict__ out) {
    __shared__ float g_lds[FCIN_];
    __shared__ float red[4];
    const int tid = threadIdx.x;
    const int b = blockIdx.x;
    for (int i = tid; i < GRED_; i += 256) g_lds[i] = g[b * GRED_ + i];
    g_lds[GRED_ + tid] = hlast[b * 256 + tid];
    __syncthreads();

    float a0 = 0.f, a1 = 0.f, a2 = 0.f, a3 = 0.f;
    for (int i = 0; i < FCIN_; i += 4) {
        a0 = fmaf(g_lds[i],     fc1Wt[(i) * 256 + tid],     a0);
        a1 = fmaf(g_lds[i + 1], fc1Wt[(i + 1) * 256 + tid], a1);
        a2 = fmaf(g_lds[i + 2], fc1Wt[(i + 2) * 256 + tid], a2);
        a3 = fmaf(g_lds[i + 3], fc1Wt[(i + 3) * 256 + tid], a3);
    }
    float acc = ((a0 + a1) + (a2 + a3)) + fc1b[tid];
    float hv = fmaxf(acc, 0.f);
    float part = hv * fc2W[tid];
    #pragma unroll
    for (int off = 32; off >= 1; off >>= 1)
        part += __shfl_down(part, off, 64);
    if ((tid & 63) == 0) red[tid >> 6] = part;
    __syncthreads();
    if (tid == 0)
        out[b] = fc2b[0] + red[0] + red[1] + red[2] + red[3];
}

// ---------------------------------------------------------------------------
extern "C" void kernel_launch(void* const* d_in, const int* in_sizes, int n_in,
                              void* d_out, int out_size, void* d_ws, size_t ws_size,
                              hipStream_t stream) {
    const float* x1     = (const float*)d_in[0];
    const float* states = (const float*)d_in[1];
    const int*   perm1  = (const int*)d_in[2];
    const int*   perm2  = (const int*)d_in[3];
    const float* Wih2   = (const float*)d_in[4];
    const float* Whh2   = (const float*)d_in[5];
    const float* bih2   = (const float*)d_in[6];
    const float* bhh2   = (const float*)d_in[7];
    const float* Wih1   = (const float*)d_in[8];
    const float* Whh1   = (const float*)d_in[9];
    const float* bih1   = (const float*)d_in[10];
    const float* bhh1   = (const float*)d_in[11];
    const float* fc1W   = (const float*)d_in[12];
    const float* fc1b   = (const float*)d_in[13];
    const float* fc2W   = (const float*)d_in[14];
    const float* fc2b   = (const float*)d_in[15];
    float* out = (float*)d_out;

    float* ws = (float*)d_ws;
    short* Bfrag   = (short*)ws;                          // 245760 bf16
    short* Bfrag1  = (short*)(ws + 122880);               // 196608 bf16
    short* Bfrag1W = (short*)(ws + 122880 + 98304);       // 712704 bf16
    float* fc1Wt   = ws + 577536;                         // 765952 f
    float* f       = fc1Wt + FCIN_ * 256;                 // 1343488
    short* fbf     = (short*)(f + 2048 * INTER_);         // 1900544 bf16
    float* xw1     = f + 2048 * INTER_ + 950272;          // 4161536
    float* hlast   = xw1 + 2048 * G3_;                    // 5734400
    float* g       = hlast + 8192;                        // 5742592 (+87552)

    prep_kernel<<<dim3(2992), 256, 0, stream>>>(Whh2, Wih2, Whh1, Wih1, fc1W,
                                                x1, Bfrag, Bfrag1, Bfrag1W,
                                                fc1Wt, f, fbf);
    gru2d_mfma<<<dim3(256), 512, 0, stream>>>(states, perm1, perm2, Bfrag,
                                              bih2, bhh2, f, fbf);
    gemm_xw1_mfma<<<dim3(12, 32), 256, 0, stream>>>(fbf, Bfrag1W, bih1, xw1);
    gru1d_freduce<<<dim3(34), 512, 0, stream>>>(xw1, Bfrag1, bhh1, hlast, f, g);
    tail_fc<<<dim3(32), 256, 0, stream>>>(g, hlast, fc1Wt, fc1b, fc2W, fc2b, out);
}